// Round 1
// baseline (674.076 us; speedup 1.0000x reference)
//
#include <hip/hip_runtime.h>

// DeepseekV3MoE on MI355X (gfx950), bf16-MFMA implementation.
// Pipeline (all on `stream`, graph-capture safe):
//  init -> gate(top2) -> scan -> assign -> cast x -> gather xg ->
//  [tcast wg -> gemm g] [tcast wu -> gemm u] -> silu(hr) ->
//  [tcast sg -> gemm gs] [tcast su -> gemm us] -> silu(hs) ->
//  [tcast sd -> gemm out(plain fp32 store)] ->
//  [tcast wd -> gemm scatter atomicAdd(w * val) into out]

typedef unsigned short u16;
typedef unsigned int   u32;
typedef __bf16 bf16x8 __attribute__((ext_vector_type(8)));
typedef float  f32x4  __attribute__((ext_vector_type(4)));

#define T_TOK 2048
#define HDIM  2048
#define IDIM  1024
#define NEXP  8
#define ISDIM 2048
#define MAXROWS 5120   // padded routed rows upper bound (4096 + 8*127 -> 5112, rounded)

__device__ __forceinline__ u16 f2bf(float f) {
  u32 x = __float_as_uint(f);
  return (u16)((x + 0x7FFFu + ((x >> 16) & 1u)) >> 16);
}
__device__ __forceinline__ float bf2f(u16 v) { return __uint_as_float(((u32)v) << 16); }

#define GLL(g, l)                                                              \
  __builtin_amdgcn_global_load_lds(                                            \
      (const __attribute__((address_space(1))) void*)(g),                      \
      (__attribute__((address_space(3))) void*)(l), 16, 0, 0)

// ---------------- init: perm = -1, counts/fill = 0 ----------------
__global__ void init_kernel(int* __restrict__ perm, int* __restrict__ meta) {
  int idx = blockIdx.x * 256 + threadIdx.x;
  if (idx < 8192) perm[idx] = -1;
  if (idx < 16) meta[idx] = 0;
}

// ---------------- gate: logits -> top2 -> renorm weights ----------------
// meta[0..7] = counts
__global__ void gate_kernel(const float* __restrict__ x, const float* __restrict__ gw,
                            float* __restrict__ topw, int* __restrict__ topi,
                            int* __restrict__ meta) {
  int t = blockIdx.x;
  int lane = threadIdx.x;  // 64
  float acc[NEXP];
#pragma unroll
  for (int e = 0; e < NEXP; e++) acc[e] = 0.f;
  const float* xr = x + (long)t * HDIM;
  for (int h = lane; h < HDIM; h += 64) {
    float xv = xr[h];
#pragma unroll
    for (int e = 0; e < NEXP; e++) acc[e] += xv * gw[e * HDIM + h];
  }
#pragma unroll
  for (int off = 32; off > 0; off >>= 1) {
#pragma unroll
    for (int e = 0; e < NEXP; e++) acc[e] += __shfl_down(acc[e], off, 64);
  }
  if (lane == 0) {
    int i0 = 0;
#pragma unroll
    for (int e = 1; e < NEXP; e++)
      if (acc[e] > acc[i0]) i0 = e;
    int i1 = -1;
#pragma unroll
    for (int e = 0; e < NEXP; e++) {
      if (e == i0) continue;
      if (i1 < 0 || acc[e] > acc[i1]) i1 = e;
    }
    // softmax -> topk -> renorm  ==  sigmoid of logit difference
    float w0 = 1.f / (1.f + __expf(acc[i1] - acc[i0]));
    float w1 = 1.f - w0;
    topw[t * 2 + 0] = w0;
    topw[t * 2 + 1] = w1;
    topi[t * 2 + 0] = i0;
    topi[t * 2 + 1] = i1;
    atomicAdd(meta + i0, 1);
    atomicAdd(meta + i1, 1);
  }
}

// ---------------- scan: padded exclusive offsets meta[16..24] ----------------
__global__ void scan_kernel(int* __restrict__ meta) {
  if (threadIdx.x == 0 && blockIdx.x == 0) {
    int o = 0;
    meta[16] = 0;
#pragma unroll
    for (int e = 0; e < NEXP; e++) {
      o += (meta[e] + 127) & ~127;
      meta[17 + e] = o;
    }
  }
}

// ---------------- assign: perm[row] = t*2+s ----------------
__global__ void assign_kernel(const int* __restrict__ topi, int* __restrict__ meta,
                              int* __restrict__ perm) {
  int idx = blockIdx.x * 256 + threadIdx.x;  // < 4096
  int e = topi[idx];
  int pos = atomicAdd(meta + 8 + e, 1);
  perm[meta[16 + e] + pos] = idx;
}

// ---------------- cast fp32 -> bf16 (8/thread) ----------------
__global__ void cast_kernel(const float* __restrict__ in, u16* __restrict__ out) {
  long i = ((long)blockIdx.x * 256 + threadIdx.x) * 8;
  float4 a = *(const float4*)(in + i);
  float4 b = *(const float4*)(in + i + 4);
  uint4 w;
  w.x = (u32)f2bf(a.x) | ((u32)f2bf(a.y) << 16);
  w.y = (u32)f2bf(a.z) | ((u32)f2bf(a.w) << 16);
  w.z = (u32)f2bf(b.x) | ((u32)f2bf(b.y) << 16);
  w.w = (u32)f2bf(b.z) | ((u32)f2bf(b.w) << 16);
  *(uint4*)(out + i) = w;
}

// ---------------- gather: xg[row] = xb[token] or zeros ----------------
__global__ void gather_kernel(const u16* __restrict__ xb, const int* __restrict__ perm,
                              const int* __restrict__ meta, u16* __restrict__ xg) {
  int r = blockIdx.x;
  if (r >= meta[24]) return;  // offp[8]
  int p = perm[r];
  u16* dst = xg + (long)r * HDIM + threadIdx.x * 8;
  if (p < 0) {
    uint4 z = {0, 0, 0, 0};
    *(uint4*)dst = z;
  } else {
    *(uint4*)dst = *(const uint4*)(xb + (long)(p >> 1) * HDIM + threadIdx.x * 8);
  }
}

// ---------------- transpose-cast: in fp32 [R][C] -> out bf16 [C][R] ----------------
__global__ __launch_bounds__(256) void tcast_kernel(const float* __restrict__ in,
                                                    u16* __restrict__ out, int R, int C) {
  __shared__ float tile[64 * 65];
  long base = (long)blockIdx.z * R * C;
  in += base;
  out += base;
  int r0 = blockIdx.y * 64, c0 = blockIdx.x * 64;
  int t = threadIdx.x;
  int i = t >> 4, j4 = t & 15;
#pragma unroll
  for (int ii = 0; ii < 4; ii++) {
    int r = i + ii * 16;
    float4 v = *(const float4*)(in + (long)(r0 + r) * C + c0 + j4 * 4);
    tile[r * 65 + j4 * 4 + 0] = v.x;
    tile[r * 65 + j4 * 4 + 1] = v.y;
    tile[r * 65 + j4 * 4 + 2] = v.z;
    tile[r * 65 + j4 * 4 + 3] = v.w;
  }
  __syncthreads();
  int cc = t >> 3, rr = (t & 7) * 8;
#pragma unroll
  for (int pp = 0; pp < 2; pp++) {
    int c = cc + pp * 32;
    u16 e[8];
#pragma unroll
    for (int u = 0; u < 8; u++) e[u] = f2bf(tile[(rr + u) * 65 + c]);
    uint4 w;
    w.x = (u32)e[0] | ((u32)e[1] << 16);
    w.y = (u32)e[2] | ((u32)e[3] << 16);
    w.z = (u32)e[4] | ((u32)e[5] << 16);
    w.w = (u32)e[6] | ((u32)e[7] << 16);
    *(uint4*)(out + (long)(c0 + c) * R + r0 + rr) = w;
  }
}

// ---------------- silu-mul: h = silu(g)*u, bf16, 8/thread ----------------
__global__ void silu_kernel(const u16* __restrict__ g, const u16* __restrict__ u,
                            u16* __restrict__ h) {
  long i = ((long)blockIdx.x * 256 + threadIdx.x) * 8;
  uint4 gv = *(const uint4*)(g + i);
  uint4 uv = *(const uint4*)(u + i);
  const u32* gp = &gv.x;
  const u32* up = &uv.x;
  uint4 w;
  u32* wp = &w.x;
#pragma unroll
  for (int j = 0; j < 4; j++) {
    float g0 = bf2f((u16)(gp[j] & 0xFFFF)), g1 = bf2f((u16)(gp[j] >> 16));
    float u0 = bf2f((u16)(up[j] & 0xFFFF)), u1 = bf2f((u16)(up[j] >> 16));
    float r0 = g0 / (1.f + __expf(-g0)) * u0;
    float r1 = g1 / (1.f + __expf(-g1)) * u1;
    wp[j] = (u32)f2bf(r0) | ((u32)f2bf(r1) << 16);
  }
  *(uint4*)(h + i) = w;
}

// ---------------- 128x128 bf16 GEMM, BK=32, m97 structure ----------------
// A [M][K] bf16 row-major, B [N][K] bf16 (pre-transposed), C = A @ B^T.
// MODE 0: bf16 store  (dense)
// MODE 1: fp32 store  (dense)
// MODE 2: bf16 store  (segmented rows: expert from offp)
// MODE 3: fp32 scatter atomicAdd(topw[p] * v) at out[(p>>1)*N+col] (segmented)
template <int MODE>
__global__ __launch_bounds__(256) void gemm128(
    const u16* __restrict__ A, const u16* __restrict__ B, u16* __restrict__ Cb,
    float* __restrict__ Cf, int N, int K, long Bstride, const int* __restrict__ offp,
    const int* __restrict__ perm, const float* __restrict__ topw) {
  const int mt = blockIdx.y, nt = blockIdx.x;
  const int row0 = mt * 128;
  const u16* Bp = B;
  if constexpr (MODE == 2 || MODE == 3) {
    if (row0 >= offp[8]) return;
    int e = 0;
    while (offp[e + 1] <= row0) ++e;
    Bp += (long)e * Bstride;
  }
  __shared__ __align__(16) u16 ldsA[128 * 32];
  __shared__ __align__(16) u16 ldsB[128 * 32];
  const int tid = threadIdx.x;
  const int c0 = tid, c1 = tid + 256;
  const u16* gA0 = A + (long)(row0 + (c0 >> 2)) * K + (c0 & 3) * 8;
  const u16* gA1 = A + (long)(row0 + (c1 >> 2)) * K + (c1 & 3) * 8;
  const u16* gB0 = Bp + (long)(nt * 128 + (c0 >> 2)) * K + (c0 & 3) * 8;
  const u16* gB1 = Bp + (long)(nt * 128 + (c1 >> 2)) * K + (c1 & 3) * 8;
  u16* lA0 = ldsA + c0 * 8;
  u16* lA1 = ldsA + c1 * 8;
  u16* lB0 = ldsB + c0 * 8;
  u16* lB1 = ldsB + c1 * 8;

  const int lane = tid & 63;
  const int wave = tid >> 6;
  const int wm = (wave & 1) * 64, wn = (wave >> 1) * 64;
  const int lrow = lane & 15, koff = (lane >> 4) * 8;
  const u16* rA = ldsA + (wm + lrow) * 32 + koff;
  const u16* rB = ldsB + (wn + lrow) * 32 + koff;

  f32x4 acc[4][4];
#pragma unroll
  for (int i = 0; i < 4; i++)
#pragma unroll
    for (int j = 0; j < 4; j++) acc[i][j] = f32x4{0.f, 0.f, 0.f, 0.f};

  const int nk = K >> 5;
  for (int kt = 0; kt < nk; ++kt) {
    const int kk = kt * 32;
    GLL(gA0 + kk, lA0);
    GLL(gA1 + kk, lA1);
    GLL(gB0 + kk, lB0);
    GLL(gB1 + kk, lB1);
    __syncthreads();
    bf16x8 af[4], bfv[4];
#pragma unroll
    for (int mi = 0; mi < 4; mi++) af[mi] = *(const bf16x8*)(rA + mi * 16 * 32);
#pragma unroll
    for (int ni = 0; ni < 4; ni++) bfv[ni] = *(const bf16x8*)(rB + ni * 16 * 32);
#pragma unroll
    for (int mi = 0; mi < 4; mi++)
#pragma unroll
      for (int ni = 0; ni < 4; ni++)
        acc[mi][ni] =
            __builtin_amdgcn_mfma_f32_16x16x32_bf16(af[mi], bfv[ni], acc[mi][ni], 0, 0, 0);
    __syncthreads();
  }

  // C/D layout: col = lane&15, row = (lane>>4)*4 + reg   [measured m89/m91]
  const int crow = row0 + wm + (lane >> 4) * 4;
  const int ccol = nt * 128 + wn + (lane & 15);
#pragma unroll
  for (int mi = 0; mi < 4; mi++) {
#pragma unroll
    for (int ni = 0; ni < 4; ni++) {
#pragma unroll
      for (int r = 0; r < 4; r++) {
        int row = crow + mi * 16 + r;
        int col = ccol + ni * 16;
        float v = acc[mi][ni][r];
        if constexpr (MODE == 0 || MODE == 2) {
          Cb[(long)row * N + col] = f2bf(v);
        } else if constexpr (MODE == 1) {
          Cf[(long)row * N + col] = v;
        } else {
          int p = perm[row];
          if (p >= 0) atomicAdd(Cf + (long)(p >> 1) * N + col, topw[p] * v);
        }
      }
    }
  }
}

extern "C" void kernel_launch(void* const* d_in, const int* in_sizes, int n_in,
                              void* d_out, int out_size, void* d_ws, size_t ws_size,
                              hipStream_t stream) {
  const float* x  = (const float*)d_in[0];
  const float* gw = (const float*)d_in[1];
  const float* wg = (const float*)d_in[2];
  const float* wu = (const float*)d_in[3];
  const float* wd = (const float*)d_in[4];
  const float* sg = (const float*)d_in[5];
  const float* su = (const float*)d_in[6];
  const float* sd = (const float*)d_in[7];
  float* out = (float*)d_out;

  char* ws = (char*)d_ws;
  size_t off = 0;
  auto alloc = [&](size_t b) {
    size_t o = off;
    off += (b + 255) & ~(size_t)255;
    return o;
  };
  u16*   wT   = (u16*)(ws + alloc((size_t)NEXP * IDIM * HDIM * 2));  // reused for all weights
  u16*   xb   = (u16*)(ws + alloc((size_t)T_TOK * HDIM * 2));
  u16*   xg   = (u16*)(ws + alloc((size_t)MAXROWS * HDIM * 2));      // later reused as hs
  u16*   gbuf = (u16*)(ws + alloc((size_t)MAXROWS * IDIM * 2));
  u16*   ubuf = (u16*)(ws + alloc((size_t)MAXROWS * IDIM * 2));
  u16*   hr   = (u16*)(ws + alloc((size_t)MAXROWS * IDIM * 2));
  float* topw = (float*)(ws + alloc((size_t)T_TOK * 2 * 4));
  int*   topi = (int*)(ws + alloc((size_t)T_TOK * 2 * 4));
  int*   perm = (int*)(ws + alloc(8192 * 4));
  int*   meta = (int*)(ws + alloc(64 * 4));  // [0..7] counts [8..15] fill [16..24] offp

  init_kernel<<<32, 256, 0, stream>>>(perm, meta);
  gate_kernel<<<T_TOK, 64, 0, stream>>>(x, gw, topw, topi, meta);
  scan_kernel<<<1, 64, 0, stream>>>(meta);
  assign_kernel<<<16, 256, 0, stream>>>(topi, meta, perm);
  cast_kernel<<<(T_TOK * HDIM) / (256 * 8), 256, 0, stream>>>(x, xb);
  gather_kernel<<<MAXROWS, 256, 0, stream>>>(xb, perm, meta, xg);

  // ---- routed up/gate projections ----
  tcast_kernel<<<dim3(IDIM / 64, HDIM / 64, NEXP), 256, 0, stream>>>(wg, wT, HDIM, IDIM);
  gemm128<2><<<dim3(IDIM / 128, MAXROWS / 128), 256, 0, stream>>>(
      xg, wT, gbuf, nullptr, IDIM, HDIM, (long)IDIM * HDIM, meta + 16, nullptr, nullptr);
  tcast_kernel<<<dim3(IDIM / 64, HDIM / 64, NEXP), 256, 0, stream>>>(wu, wT, HDIM, IDIM);
  gemm128<2><<<dim3(IDIM / 128, MAXROWS / 128), 256, 0, stream>>>(
      xg, wT, ubuf, nullptr, IDIM, HDIM, (long)IDIM * HDIM, meta + 16, nullptr, nullptr);
  silu_kernel<<<(MAXROWS * IDIM) / (256 * 8), 256, 0, stream>>>(gbuf, ubuf, hr);

  // ---- shared experts ----
  tcast_kernel<<<dim3(ISDIM / 64, HDIM / 64, 1), 256, 0, stream>>>(sg, wT, HDIM, ISDIM);
  gemm128<0><<<dim3(ISDIM / 128, T_TOK / 128), 256, 0, stream>>>(
      xb, wT, gbuf, nullptr, ISDIM, HDIM, 0, nullptr, nullptr, nullptr);
  tcast_kernel<<<dim3(ISDIM / 64, HDIM / 64, 1), 256, 0, stream>>>(su, wT, HDIM, ISDIM);
  gemm128<0><<<dim3(ISDIM / 128, T_TOK / 128), 256, 0, stream>>>(
      xb, wT, ubuf, nullptr, ISDIM, HDIM, 0, nullptr, nullptr, nullptr);
  silu_kernel<<<(T_TOK * ISDIM) / (256 * 8), 256, 0, stream>>>(gbuf, ubuf, xg);  // hs in xg
  tcast_kernel<<<dim3(HDIM / 64, ISDIM / 64, 1), 256, 0, stream>>>(sd, wT, ISDIM, HDIM);
  gemm128<1><<<dim3(HDIM / 128, T_TOK / 128), 256, 0, stream>>>(
      xg, wT, nullptr, out, HDIM, ISDIM, 0, nullptr, nullptr, nullptr);

  // ---- routed down projection + weighted scatter (after shared plain stores) ----
  tcast_kernel<<<dim3(HDIM / 64, IDIM / 64, NEXP), 256, 0, stream>>>(wd, wT, IDIM, HDIM);
  gemm128<3><<<dim3(HDIM / 128, MAXROWS / 128), 256, 0, stream>>>(
      hr, wT, nullptr, out, HDIM, IDIM, (long)HDIM * IDIM, meta + 16, perm, topw);
}

// Round 2
// 576.274 us; speedup vs baseline: 1.1697x; 1.1697x over previous
//
#include <hip/hip_runtime.h>

// DeepseekV3MoE on MI355X (gfx950), bf16-MFMA, round 2.
// - gate fused with x->bf16 cast and out zeroing (256 thr/token)
// - gather-free GEMM A-staging via perm indirection (+4KB zero row)
// - XOR LDS chunk swizzle (GLL-compatible) to kill 8-way ds_read_b128 conflicts
// - fused launches: [routed gu + shared gu], [shared down + routed down scatter]
//   (down epilogues are atomicAdd into pre-zeroed out -> ordering-free)
// - runtime ws_size branch: fully-fused weights (~130MB) vs sequential (~88MB)

typedef unsigned short u16;
typedef unsigned int   u32;
typedef __bf16 bf16x8 __attribute__((ext_vector_type(8)));
typedef float  f32x4  __attribute__((ext_vector_type(4)));

#define T_TOK 2048
#define HDIM  2048
#define IDIM  1024
#define NEXP  8
#define ISDIM 2048
#define MAXROWS 5120   // 4096 + 8*127 -> 5112, rounded up to 128-multiple

__device__ __forceinline__ u16 f2bf(float f) {
  u32 x = __float_as_uint(f);
  return (u16)((x + 0x7FFFu + ((x >> 16) & 1u)) >> 16);
}
__device__ __forceinline__ float bf2f(u16 v) { return __uint_as_float(((u32)v) << 16); }

#define GLL(g, l)                                                              \
  __builtin_amdgcn_global_load_lds(                                            \
      (const __attribute__((address_space(1))) void*)(g),                      \
      (__attribute__((address_space(3))) void*)(l), 16, 0, 0)

// ---------------- init: perm=-1, meta=0, zrow=0 ----------------
__global__ void init_kernel(int* __restrict__ perm, int* __restrict__ meta,
                            int* __restrict__ zrow) {
  int idx = blockIdx.x * 256 + threadIdx.x;
  if (idx < 8192) perm[idx] = -1;
  if (idx < 16) meta[idx] = 0;
  if (idx < 1024) zrow[idx] = 0;
}

// ---------------- gate: logits->top2->renorm; fused x cast + out zero ----------------
__global__ __launch_bounds__(256) void gate_kernel(
    const float* __restrict__ x, const float* __restrict__ gw,
    u16* __restrict__ xb, float* __restrict__ outz,
    float* __restrict__ topw, int* __restrict__ topi, int* __restrict__ meta) {
  const int t = blockIdx.x, tid = threadIdx.x;
  const long o = (long)t * HDIM + tid * 8;
  float4 a = *(const float4*)(x + o);
  float4 b = *(const float4*)(x + o + 4);
  float4 z = {0.f, 0.f, 0.f, 0.f};
  *(float4*)(outz + o) = z;
  *(float4*)(outz + o + 4) = z;
  uint4 w;
  w.x = (u32)f2bf(a.x) | ((u32)f2bf(a.y) << 16);
  w.y = (u32)f2bf(a.z) | ((u32)f2bf(a.w) << 16);
  w.z = (u32)f2bf(b.x) | ((u32)f2bf(b.y) << 16);
  w.w = (u32)f2bf(b.z) | ((u32)f2bf(b.w) << 16);
  *(uint4*)(xb + o) = w;
  float acc[NEXP];
#pragma unroll
  for (int e = 0; e < NEXP; e++) {
    const float* gr = gw + e * HDIM + tid * 8;
    float4 wa = *(const float4*)gr;
    float4 wb = *(const float4*)(gr + 4);
    acc[e] = a.x * wa.x + a.y * wa.y + a.z * wa.z + a.w * wa.w +
             b.x * wb.x + b.y * wb.y + b.z * wb.z + b.w * wb.w;
  }
#pragma unroll
  for (int off = 32; off; off >>= 1)
#pragma unroll
    for (int e = 0; e < NEXP; e++) acc[e] += __shfl_down(acc[e], off, 64);
  __shared__ float red[4][NEXP];
  if ((tid & 63) == 0) {
#pragma unroll
    for (int e = 0; e < NEXP; e++) red[tid >> 6][e] = acc[e];
  }
  __syncthreads();
  if (tid == 0) {
    float s[NEXP];
#pragma unroll
    for (int e = 0; e < NEXP; e++) s[e] = red[0][e] + red[1][e] + red[2][e] + red[3][e];
    int i0 = 0;
#pragma unroll
    for (int e = 1; e < NEXP; e++)
      if (s[e] > s[i0]) i0 = e;
    int i1 = -1;
#pragma unroll
    for (int e = 0; e < NEXP; e++) {
      if (e == i0) continue;
      if (i1 < 0 || s[e] > s[i1]) i1 = e;
    }
    float w0 = 1.f / (1.f + __expf(s[i1] - s[i0]));  // softmax->top2->renorm
    topw[t * 2 + 0] = w0;
    topw[t * 2 + 1] = 1.f - w0;
    topi[t * 2 + 0] = i0;
    topi[t * 2 + 1] = i1;
    atomicAdd(meta + i0, 1);
    atomicAdd(meta + i1, 1);
  }
}

// ---------------- scan: padded exclusive offsets meta[16..24] ----------------
__global__ void scan_kernel(int* __restrict__ meta) {
  if (threadIdx.x == 0 && blockIdx.x == 0) {
    int o = 0;
    meta[16] = 0;
#pragma unroll
    for (int e = 0; e < NEXP; e++) {
      o += (meta[e] + 127) & ~127;
      meta[17 + e] = o;
    }
  }
}

// ---------------- assign: perm[row] = t*2+slot ----------------
__global__ void assign_kernel(const int* __restrict__ topi, int* __restrict__ meta,
                              int* __restrict__ perm) {
  int idx = blockIdx.x * 256 + threadIdx.x;  // < 4096
  int e = topi[idx];
  int pos = atomicAdd(meta + 8 + e, 1);
  perm[meta[16 + e] + pos] = idx;
}

// ---------------- transpose-cast: fp32 [R][C] -> bf16 [C][R], z-strided ----------------
__global__ __launch_bounds__(256) void tcast_kernel(const float* __restrict__ in,
                                                    u16* __restrict__ out, int R, int C,
                                                    long inz, long outz) {
  __shared__ float tile[64 * 65];
  in += (long)blockIdx.z * inz;
  out += (long)blockIdx.z * outz;
  int r0 = blockIdx.y * 64, c0 = blockIdx.x * 64;
  int t = threadIdx.x;
  int i = t >> 4, j4 = t & 15;
#pragma unroll
  for (int ii = 0; ii < 4; ii++) {
    int r = i + ii * 16;
    float4 v = *(const float4*)(in + (long)(r0 + r) * C + c0 + j4 * 4);
    tile[r * 65 + j4 * 4 + 0] = v.x;
    tile[r * 65 + j4 * 4 + 1] = v.y;
    tile[r * 65 + j4 * 4 + 2] = v.z;
    tile[r * 65 + j4 * 4 + 3] = v.w;
  }
  __syncthreads();
  int cc = t >> 3, rr = (t & 7) * 8;
#pragma unroll
  for (int pp = 0; pp < 2; pp++) {
    int c = cc + pp * 32;
    u16 e[8];
#pragma unroll
    for (int u = 0; u < 8; u++) e[u] = f2bf(tile[(rr + u) * 65 + c]);
    uint4 w;
    w.x = (u32)e[0] | ((u32)e[1] << 16);
    w.y = (u32)e[2] | ((u32)e[3] << 16);
    w.z = (u32)e[4] | ((u32)e[5] << 16);
    w.w = (u32)e[6] | ((u32)e[7] << 16);
    *(uint4*)(out + (long)(c0 + c) * R + r0 + rr) = w;
  }
}

// ---------------- silu-mul in place: buf[r][c] = silu(buf[r][c]) * buf[r][half+c] ----------------
template <int HALF8>  // half / 8
__global__ void silu_kernel(u16* __restrict__ buf) {
  long i = (long)blockIdx.x * 256 + threadIdx.x;
  long r = i / HALF8, c = i % HALF8;
  u16* g = buf + r * (long)HALF8 * 16 + c * 8;
  uint4 gv = *(const uint4*)g;
  uint4 uv = *(const uint4*)(g + HALF8 * 8);
  const u32* gp = &gv.x;
  const u32* up = &uv.x;
  uint4 w;
  u32* wp = &w.x;
#pragma unroll
  for (int j = 0; j < 4; j++) {
    float g0 = bf2f((u16)(gp[j] & 0xFFFF)), g1 = bf2f((u16)(gp[j] >> 16));
    float u0 = bf2f((u16)(up[j] & 0xFFFF)), u1 = bf2f((u16)(up[j] >> 16));
    float r0 = g0 / (1.f + __expf(-g0)) * u0;
    float r1 = g1 / (1.f + __expf(-g1)) * u1;
    wp[j] = (u32)f2bf(r0) | ((u32)f2bf(r1) << 16);
  }
  *(uint4*)g = w;
}

// ---------------- 128x128x(BK32) bf16 GEMM tile body, m97 structure + XOR swizzle ------
// A [.][lda] bf16 (rows direct, or via perm -> xb token rows / zrow), B [n][K] k-fast.
// CMODE 0: bf16 store (ldc).  1: fp32 atomicAdd at A-row.  2: fp32 atomicAdd scatter
//          at token row perm[row]>>1 weighted by topw[perm[row]].
template <int CMODE, bool PERMA, bool SEGB>
__device__ __forceinline__ void gemm_body(
    int mt, int nt, u16* ldsA, u16* ldsB, const u16* __restrict__ A, long lda,
    const u16* __restrict__ B, long ldbz, int K, u16* __restrict__ Cb,
    float* __restrict__ Cf, long ldc, const int* __restrict__ offp,
    const int* __restrict__ perm, const float* __restrict__ topw,
    const u16* __restrict__ zrow) {
  const int row0 = mt * 128;
  if constexpr (SEGB) {
    if (row0 >= offp[8]) return;
    int e = 0;
    while (offp[e + 1] <= row0) ++e;
    B += (long)e * ldbz;
  }
  const int tid = threadIdx.x;
  const int c0 = tid, c1 = tid + 256;
  // XOR swizzle: LDS slot s of row r holds global k-chunk s ^ ((r>>1)&3).
  const int sw0 = (((c0 & 3) ^ ((c0 >> 3) & 3)) * 8);
  const int sw1 = (((c1 & 3) ^ ((c1 >> 3) & 3)) * 8);
  const u16 *ar0, *ar1;
  if constexpr (PERMA) {
    int p0 = perm[row0 + (c0 >> 2)];
    int p1 = perm[row0 + (c1 >> 2)];
    ar0 = (p0 < 0) ? zrow : A + (long)(p0 >> 1) * lda;
    ar1 = (p1 < 0) ? zrow : A + (long)(p1 >> 1) * lda;
  } else {
    ar0 = A + (long)(row0 + (c0 >> 2)) * lda;
    ar1 = A + (long)(row0 + (c1 >> 2)) * lda;
  }
  const u16* gA0 = ar0 + sw0;
  const u16* gA1 = ar1 + sw1;
  const u16* gB0 = B + (long)(nt * 128 + (c0 >> 2)) * K + sw0;
  const u16* gB1 = B + (long)(nt * 128 + (c1 >> 2)) * K + sw1;
  u16* lA0 = ldsA + c0 * 8;
  u16* lA1 = ldsA + c1 * 8;
  u16* lB0 = ldsB + c0 * 8;
  u16* lB1 = ldsB + c1 * 8;

  const int lane = tid & 63, wave = tid >> 6;
  const int wm = (wave & 1) * 64, wn = (wave >> 1) * 64;
  const int lrow = lane & 15;
  const int ksw = (((lane >> 4) ^ ((lrow >> 1) & 3)) * 8);
  const u16* rA = ldsA + (wm + lrow) * 32 + ksw;
  const u16* rB = ldsB + (wn + lrow) * 32 + ksw;

  f32x4 acc[4][4];
#pragma unroll
  for (int i = 0; i < 4; i++)
#pragma unroll
    for (int j = 0; j < 4; j++) acc[i][j] = f32x4{0.f, 0.f, 0.f, 0.f};

  const int nk = K >> 5;
  for (int kt = 0; kt < nk; ++kt) {
    const int kk = kt * 32;
    GLL(gA0 + kk, lA0);
    GLL(gA1 + kk, lA1);
    GLL(gB0 + kk, lB0);
    GLL(gB1 + kk, lB1);
    __syncthreads();
    bf16x8 af[4], bfv[4];
#pragma unroll
    for (int mi = 0; mi < 4; mi++) af[mi] = *(const bf16x8*)(rA + mi * 16 * 32);
#pragma unroll
    for (int ni = 0; ni < 4; ni++) bfv[ni] = *(const bf16x8*)(rB + ni * 16 * 32);
#pragma unroll
    for (int mi = 0; mi < 4; mi++)
#pragma unroll
      for (int ni = 0; ni < 4; ni++)
        acc[mi][ni] =
            __builtin_amdgcn_mfma_f32_16x16x32_bf16(af[mi], bfv[ni], acc[mi][ni], 0, 0, 0);
    __syncthreads();
  }

  // C/D layout: col = lane&15, row = (lane>>4)*4 + reg   [measured m89/m91]
  const int crow = row0 + wm + ((lane >> 4) << 2);
  const int ccol = nt * 128 + wn + (lane & 15);
#pragma unroll
  for (int mi = 0; mi < 4; mi++) {
#pragma unroll
    for (int ni = 0; ni < 4; ni++) {
#pragma unroll
      for (int r = 0; r < 4; r++) {
        int row = crow + mi * 16 + r;
        int col = ccol + ni * 16;
        float v = acc[mi][ni][r];
        if constexpr (CMODE == 0) {
          Cb[(long)row * ldc + col] = f2bf(v);
        } else if constexpr (CMODE == 1) {
          atomicAdd(Cf + (long)row * ldc + col, v);
        } else {
          int p = perm[row];
          if (p >= 0) atomicAdd(Cf + (long)(p >> 1) * ldc + col, topw[p] * v);
        }
      }
    }
  }
}

// ---- fused [routed gu | shared gu]: 640 + 512 blocks ----
__global__ __launch_bounds__(256) void gemm_gu_fused(
    const u16* __restrict__ xb, const u16* __restrict__ wguT,
    const u16* __restrict__ sgsuT, u16* __restrict__ gur, u16* __restrict__ gus,
    const int* __restrict__ offp, const int* __restrict__ perm,
    const u16* __restrict__ zrow) {
  __shared__ __align__(16) u16 ldsA[4096], ldsB[4096];
  int bid = blockIdx.x;
  if (bid < 640) {
    gemm_body<0, true, true>(bid / 16, bid % 16, ldsA, ldsB, xb, HDIM, wguT,
                             (long)2 * IDIM * HDIM, HDIM, gur, nullptr, 2 * IDIM, offp,
                             perm, nullptr, zrow);
  } else {
    int b = bid - 640;
    gemm_body<0, false, false>(b / 32, b % 32, ldsA, ldsB, xb, HDIM, sgsuT, 0, HDIM, gus,
                               nullptr, 2 * ISDIM, nullptr, nullptr, nullptr, nullptr);
  }
}

// ---- fallback: routed g or u alone (B = per-expert [I][H]) ----
__global__ __launch_bounds__(256) void gemm_routed_gu(
    const u16* __restrict__ xb, const u16* __restrict__ wT, u16* __restrict__ Cb,
    const int* __restrict__ offp, const int* __restrict__ perm,
    const u16* __restrict__ zrow) {
  __shared__ __align__(16) u16 ldsA[4096], ldsB[4096];
  gemm_body<0, true, true>(blockIdx.y, blockIdx.x, ldsA, ldsB, xb, HDIM, wT,
                           (long)IDIM * HDIM, HDIM, Cb, nullptr, 2 * IDIM, offp, perm,
                           nullptr, zrow);
}

// ---- fallback: shared gu (N = 2*IS) ----
__global__ __launch_bounds__(256) void gemm_shared_gu(const u16* __restrict__ xb,
                                                      const u16* __restrict__ sgsuT,
                                                      u16* __restrict__ gus) {
  __shared__ __align__(16) u16 ldsA[4096], ldsB[4096];
  gemm_body<0, false, false>(blockIdx.y, blockIdx.x, ldsA, ldsB, xb, HDIM, sgsuT, 0, HDIM,
                             gus, nullptr, 2 * ISDIM, nullptr, nullptr, nullptr, nullptr);
}

// ---- fused [shared down | routed down scatter]: 256 + 640 blocks, atomics into zeroed out
__global__ __launch_bounds__(256) void gemm_down_fused(
    const u16* __restrict__ gus, const u16* __restrict__ sdT,
    const u16* __restrict__ gur, const u16* __restrict__ wdT, float* __restrict__ out,
    const int* __restrict__ offp, const int* __restrict__ perm,
    const float* __restrict__ topw) {
  __shared__ __align__(16) u16 ldsA[4096], ldsB[4096];
  int bid = blockIdx.x;
  if (bid < 256) {
    gemm_body<1, false, false>(bid / 16, bid % 16, ldsA, ldsB, gus, 2 * ISDIM, sdT, 0,
                               ISDIM, nullptr, out, HDIM, nullptr, nullptr, nullptr,
                               nullptr);
  } else {
    int b = bid - 256;
    gemm_body<2, false, true>(b / 16, b % 16, ldsA, ldsB, gur, 2 * IDIM, wdT,
                              (long)HDIM * IDIM, IDIM, nullptr, out, HDIM, offp, perm,
                              topw, nullptr);
  }
}

extern "C" void kernel_launch(void* const* d_in, const int* in_sizes, int n_in,
                              void* d_out, int out_size, void* d_ws, size_t ws_size,
                              hipStream_t stream) {
  const float* x  = (const float*)d_in[0];
  const float* gw = (const float*)d_in[1];
  const float* wg = (const float*)d_in[2];
  const float* wu = (const float*)d_in[3];
  const float* wd = (const float*)d_in[4];
  const float* sg = (const float*)d_in[5];
  const float* su = (const float*)d_in[6];
  const float* sd = (const float*)d_in[7];
  float* out = (float*)d_out;

  char* ws = (char*)d_ws;
  size_t off = 0;
  auto alloc = [&](size_t b) {
    size_t o = off;
    off += (b + 255) & ~(size_t)255;
    return (void*)(ws + o);
  };
  u16*   xb   = (u16*)alloc((size_t)T_TOK * HDIM * 2);
  u16*   gur  = (u16*)alloc((size_t)MAXROWS * 2 * IDIM * 2);   // g|u, hr in place (cols 0..I)
  u16*   gus  = (u16*)alloc((size_t)T_TOK * 2 * ISDIM * 2);    // gs|us, hs in place
  float* topw = (float*)alloc((size_t)T_TOK * 2 * 4);
  int*   topi = (int*)alloc((size_t)T_TOK * 2 * 4);
  int*   perm = (int*)alloc(8192 * 4);
  int*   meta = (int*)alloc(64 * 4);  // [0..7] cnt [8..15] fill [16..24] padded offsets
  u16*   zrow = (u16*)alloc(4096);
  size_t base = off;

  const size_t SZ_WGUT  = (size_t)NEXP * 2 * IDIM * HDIM * 2;  // 64 MiB
  const size_t SZ_SGSUT = (size_t)2 * ISDIM * HDIM * 2;        // 16 MiB
  const size_t SZ_SDT   = (size_t)HDIM * ISDIM * 2;            // 8 MiB
  const size_t SZ_WDT   = (size_t)NEXP * HDIM * IDIM * 2;      // 32 MiB
  const bool fused = ws_size >= base + SZ_WGUT + SZ_SGSUT;

  init_kernel<<<32, 256, 0, stream>>>(perm, meta, (int*)zrow);
  gate_kernel<<<T_TOK, 256, 0, stream>>>(x, gw, xb, out, topw, topi, meta);
  scan_kernel<<<1, 64, 0, stream>>>(meta);
  assign_kernel<<<16, 256, 0, stream>>>(topi, meta, perm);

  if (fused) {
    u16* wguT  = (u16*)(ws + base);
    u16* sgsuT = (u16*)(ws + base + SZ_WGUT);
    u16* sdT   = wguT;                 // reuse after gu gemm
    u16* wdT   = wguT + SZ_SDT / 2;    // element offset
    tcast_kernel<<<dim3(IDIM / 64, HDIM / 64, NEXP), 256, 0, stream>>>(
        wg, wguT, HDIM, IDIM, (long)HDIM * IDIM, (long)2 * IDIM * HDIM);
    tcast_kernel<<<dim3(IDIM / 64, HDIM / 64, NEXP), 256, 0, stream>>>(
        wu, wguT + (size_t)IDIM * HDIM, HDIM, IDIM, (long)HDIM * IDIM,
        (long)2 * IDIM * HDIM);
    tcast_kernel<<<dim3(ISDIM / 64, HDIM / 64, 1), 256, 0, stream>>>(sg, sgsuT, HDIM,
                                                                     ISDIM, 0, 0);
    tcast_kernel<<<dim3(ISDIM / 64, HDIM / 64, 1), 256, 0, stream>>>(
        su, sgsuT + (size_t)ISDIM * HDIM, HDIM, ISDIM, 0, 0);
    gemm_gu_fused<<<1152, 256, 0, stream>>>(xb, wguT, sgsuT, gur, gus, meta + 16, perm,
                                            zrow);
    silu_kernel<128><<<(MAXROWS * IDIM / 8) / 256, 256, 0, stream>>>(gur);
    silu_kernel<256><<<(T_TOK * ISDIM / 8) / 256, 256, 0, stream>>>(gus);
    tcast_kernel<<<dim3(HDIM / 64, ISDIM / 64, 1), 256, 0, stream>>>(sd, sdT, ISDIM,
                                                                     HDIM, 0, 0);
    tcast_kernel<<<dim3(HDIM / 64, IDIM / 64, NEXP), 256, 0, stream>>>(
        wd, wdT, IDIM, HDIM, (long)IDIM * HDIM, (long)HDIM * IDIM);
    gemm_down_fused<<<896, 256, 0, stream>>>(gus, sdT, gur, wdT, out, meta + 16, perm,
                                             topw);
  } else {
    u16* wT    = (u16*)(ws + base);    // 40 MiB region, sequentially reused
    u16* sgsuT = wT;
    u16* sdT   = wT;
    u16* wdT   = wT + SZ_SDT / 2;
    tcast_kernel<<<dim3(IDIM / 64, HDIM / 64, NEXP), 256, 0, stream>>>(
        wg, wT, HDIM, IDIM, (long)HDIM * IDIM, (long)IDIM * HDIM);
    gemm_routed_gu<<<dim3(8, MAXROWS / 128), 256, 0, stream>>>(xb, wT, gur, meta + 16,
                                                               perm, zrow);
    tcast_kernel<<<dim3(IDIM / 64, HDIM / 64, NEXP), 256, 0, stream>>>(
        wu, wT, HDIM, IDIM, (long)HDIM * IDIM, (long)IDIM * HDIM);
    gemm_routed_gu<<<dim3(8, MAXROWS / 128), 256, 0, stream>>>(xb, wT, gur + IDIM,
                                                               meta + 16, perm, zrow);
    silu_kernel<128><<<(MAXROWS * IDIM / 8) / 256, 256, 0, stream>>>(gur);
    tcast_kernel<<<dim3(ISDIM / 64, HDIM / 64, 1), 256, 0, stream>>>(sg, sgsuT, HDIM,
                                                                     ISDIM, 0, 0);
    tcast_kernel<<<dim3(ISDIM / 64, HDIM / 64, 1), 256, 0, stream>>>(
        su, sgsuT + (size_t)ISDIM * HDIM, HDIM, ISDIM, 0, 0);
    gemm_shared_gu<<<dim3(32, 16), 256, 0, stream>>>(xb, sgsuT, gus);
    silu_kernel<256><<<(T_TOK * ISDIM / 8) / 256, 256, 0, stream>>>(gus);
    tcast_kernel<<<dim3(HDIM / 64, ISDIM / 64, 1), 256, 0, stream>>>(sd, sdT, ISDIM,
                                                                     HDIM, 0, 0);
    tcast_kernel<<<dim3(HDIM / 64, IDIM / 64, NEXP), 256, 0, stream>>>(
        wd, wdT, IDIM, HDIM, (long)IDIM * HDIM, (long)HDIM * IDIM);
    gemm_down_fused<<<896, 256, 0, stream>>>(gus, sdT, gur, wdT, out, meta + 16, perm,
                                             topw);
  }
}

// Round 4
// 517.938 us; speedup vs baseline: 1.3015x; 1.1126x over previous
//
#include <hip/hip_runtime.h>

// DeepseekV3MoE on MI355X (gfx950), bf16-MFMA, round 4 (= round 3 with the
// combine_kernel placeholder-loop bug removed).
// - atomics eliminated on fused path: shared-down plain fp32 stores to out,
//   routed-down bf16 stores to eo, final combine kernel adds weighted eo rows
// - BK=64 K-loop (32 KB LDS, 32 MFMA per barrier) to halve barrier drains
// - XOR chunk swizzle (slot = chunk ^ (row&7)) -> 2-way LDS aliasing (free)
// - gather-free A staging via perm indirection (+4KB zero row)

typedef unsigned short u16;
typedef unsigned int   u32;
typedef __bf16 bf16x8 __attribute__((ext_vector_type(8)));
typedef float  f32x4  __attribute__((ext_vector_type(4)));

#define T_TOK 2048
#define HDIM  2048
#define IDIM  1024
#define NEXP  8
#define ISDIM 2048
#define MAXROWS 5120   // 4096 + 8*127 -> 5112, rounded up to 128-multiple

__device__ __forceinline__ u16 f2bf(float f) {
  u32 x = __float_as_uint(f);
  return (u16)((x + 0x7FFFu + ((x >> 16) & 1u)) >> 16);
}
__device__ __forceinline__ float bf2f(u16 v) { return __uint_as_float(((u32)v) << 16); }

#define GLL(g, l)                                                              \
  __builtin_amdgcn_global_load_lds(                                            \
      (const __attribute__((address_space(1))) void*)(g),                      \
      (__attribute__((address_space(3))) void*)(l), 16, 0, 0)

// ---------------- init: perm=-1, meta=0, zrow=0 ----------------
__global__ void init_kernel(int* __restrict__ perm, int* __restrict__ meta,
                            int* __restrict__ zrow) {
  int idx = blockIdx.x * 256 + threadIdx.x;
  if (idx < 8192) perm[idx] = -1;
  if (idx < 16) meta[idx] = 0;
  if (idx < 1024) zrow[idx] = 0;
}

// ---------------- gate: logits->top2->renorm; fused x cast + out zero ----------------
__global__ __launch_bounds__(256) void gate_kernel(
    const float* __restrict__ x, const float* __restrict__ gw,
    u16* __restrict__ xb, float* __restrict__ outz,
    float* __restrict__ topw, int* __restrict__ topi, int* __restrict__ meta) {
  const int t = blockIdx.x, tid = threadIdx.x;
  const long o = (long)t * HDIM + tid * 8;
  float4 a = *(const float4*)(x + o);
  float4 b = *(const float4*)(x + o + 4);
  float4 z = {0.f, 0.f, 0.f, 0.f};
  *(float4*)(outz + o) = z;
  *(float4*)(outz + o + 4) = z;
  uint4 w;
  w.x = (u32)f2bf(a.x) | ((u32)f2bf(a.y) << 16);
  w.y = (u32)f2bf(a.z) | ((u32)f2bf(a.w) << 16);
  w.z = (u32)f2bf(b.x) | ((u32)f2bf(b.y) << 16);
  w.w = (u32)f2bf(b.z) | ((u32)f2bf(b.w) << 16);
  *(uint4*)(xb + o) = w;
  float acc[NEXP];
#pragma unroll
  for (int e = 0; e < NEXP; e++) {
    const float* gr = gw + e * HDIM + tid * 8;
    float4 wa = *(const float4*)gr;
    float4 wb = *(const float4*)(gr + 4);
    acc[e] = a.x * wa.x + a.y * wa.y + a.z * wa.z + a.w * wa.w +
             b.x * wb.x + b.y * wb.y + b.z * wb.z + b.w * wb.w;
  }
#pragma unroll
  for (int off = 32; off; off >>= 1)
#pragma unroll
    for (int e = 0; e < NEXP; e++) acc[e] += __shfl_down(acc[e], off, 64);
  __shared__ float red[4][NEXP];
  if ((tid & 63) == 0) {
#pragma unroll
    for (int e = 0; e < NEXP; e++) red[tid >> 6][e] = acc[e];
  }
  __syncthreads();
  if (tid == 0) {
    float s[NEXP];
#pragma unroll
    for (int e = 0; e < NEXP; e++) s[e] = red[0][e] + red[1][e] + red[2][e] + red[3][e];
    int i0 = 0;
#pragma unroll
    for (int e = 1; e < NEXP; e++)
      if (s[e] > s[i0]) i0 = e;
    int i1 = -1;
#pragma unroll
    for (int e = 0; e < NEXP; e++) {
      if (e == i0) continue;
      if (i1 < 0 || s[e] > s[i1]) i1 = e;
    }
    float w0 = 1.f / (1.f + __expf(s[i1] - s[i0]));  // softmax->top2->renorm
    topw[t * 2 + 0] = w0;
    topw[t * 2 + 1] = 1.f - w0;
    topi[t * 2 + 0] = i0;
    topi[t * 2 + 1] = i1;
    atomicAdd(meta + i0, 1);
    atomicAdd(meta + i1, 1);
  }
}

// ---------------- scan: padded exclusive offsets meta[16..24] ----------------
__global__ void scan_kernel(int* __restrict__ meta) {
  if (threadIdx.x == 0 && blockIdx.x == 0) {
    int o = 0;
    meta[16] = 0;
#pragma unroll
    for (int e = 0; e < NEXP; e++) {
      o += (meta[e] + 127) & ~127;
      meta[17 + e] = o;
    }
  }
}

// ---------------- assign: perm[row]=t*2+slot, tokrow[t*2+slot]=row ----------------
__global__ void assign_kernel(const int* __restrict__ topi, int* __restrict__ meta,
                              int* __restrict__ perm, int* __restrict__ tokrow) {
  int idx = blockIdx.x * 256 + threadIdx.x;  // < 4096
  int e = topi[idx];
  int pos = atomicAdd(meta + 8 + e, 1);
  int row = meta[16 + e] + pos;
  perm[row] = idx;
  tokrow[idx] = row;
}

// ---------------- transpose-cast: fp32 [R][C] -> bf16 [C][R], z-strided ----------------
__global__ __launch_bounds__(256) void tcast_kernel(const float* __restrict__ in,
                                                    u16* __restrict__ out, int R, int C,
                                                    long inz, long outz) {
  __shared__ float tile[64 * 65];
  in += (long)blockIdx.z * inz;
  out += (long)blockIdx.z * outz;
  int r0 = blockIdx.y * 64, c0 = blockIdx.x * 64;
  int t = threadIdx.x;
  int i = t >> 4, j4 = t & 15;
#pragma unroll
  for (int ii = 0; ii < 4; ii++) {
    int r = i + ii * 16;
    float4 v = *(const float4*)(in + (long)(r0 + r) * C + c0 + j4 * 4);
    tile[r * 65 + j4 * 4 + 0] = v.x;
    tile[r * 65 + j4 * 4 + 1] = v.y;
    tile[r * 65 + j4 * 4 + 2] = v.z;
    tile[r * 65 + j4 * 4 + 3] = v.w;
  }
  __syncthreads();
  int cc = t >> 3, rr = (t & 7) * 8;
#pragma unroll
  for (int pp = 0; pp < 2; pp++) {
    int c = cc + pp * 32;
    u16 e[8];
#pragma unroll
    for (int u = 0; u < 8; u++) e[u] = f2bf(tile[(rr + u) * 65 + c]);
    uint4 w;
    w.x = (u32)e[0] | ((u32)e[1] << 16);
    w.y = (u32)e[2] | ((u32)e[3] << 16);
    w.z = (u32)e[4] | ((u32)e[5] << 16);
    w.w = (u32)e[6] | ((u32)e[7] << 16);
    *(uint4*)(out + (long)(c0 + c) * R + r0 + rr) = w;
  }
}

// ---------------- silu-mul in place ----------------
template <int HALF8>  // half-width / 8
__global__ void silu_kernel(u16* __restrict__ buf) {
  long i = (long)blockIdx.x * 256 + threadIdx.x;
  long r = i / HALF8, c = i % HALF8;
  u16* g = buf + r * (long)HALF8 * 16 + c * 8;
  uint4 gv = *(const uint4*)g;
  uint4 uv = *(const uint4*)(g + HALF8 * 8);
  const u32* gp = &gv.x;
  const u32* up = &uv.x;
  uint4 w;
  u32* wp = &w.x;
#pragma unroll
  for (int j = 0; j < 4; j++) {
    float g0 = bf2f((u16)(gp[j] & 0xFFFF)), g1 = bf2f((u16)(gp[j] >> 16));
    float u0 = bf2f((u16)(up[j] & 0xFFFF)), u1 = bf2f((u16)(up[j] >> 16));
    float r0 = g0 / (1.f + __expf(-g0)) * u0;
    float r1 = g1 / (1.f + __expf(-g1)) * u1;
    wp[j] = (u32)f2bf(r0) | ((u32)f2bf(r1) << 16);
  }
  *(uint4*)g = w;
}

// -------- 128x128 tile, BK=64 bf16 GEMM body, XOR-swizzled LDS --------
// A [.][lda] (rows direct or perm->token rows / zrow), B [n][K] k-fast.
// CMODE 0: bf16 plain store. 1: fp32 plain store. 2: fp32 atomic scatter
// (token row perm[row]>>1, weight topw). 3: fp32 atomicAdd at tile row.
template <int CMODE, bool PERMA, bool SEGB>
__device__ __forceinline__ void gemm_body(
    int mt, int nt, u16* ldsA, u16* ldsB, const u16* __restrict__ A, long lda,
    const u16* __restrict__ B, long ldbz, int K, u16* __restrict__ Cb,
    float* __restrict__ Cf, long ldc, const int* __restrict__ offp,
    const int* __restrict__ perm, const float* __restrict__ topw,
    const u16* __restrict__ zrow) {
  const int row0 = mt * 128;
  if constexpr (SEGB) {
    if (row0 >= offp[8]) return;
    int e = 0;
    while (offp[e + 1] <= row0) ++e;
    B += (long)e * ldbz;
  }
  const int tid = threadIdx.x;
  const u16* gA[4];
  const u16* gB[4];
  u16 *lA[4], *lB[4];
#pragma unroll
  for (int j = 0; j < 4; j++) {
    int c = tid + 256 * j;
    int r = c >> 3, s = c & 7;
    int gk = (s ^ (r & 7)) * 8;  // swizzled global chunk
    const u16* arow;
    if constexpr (PERMA) {
      int p = perm[row0 + r];
      arow = (p < 0) ? zrow : A + (long)(p >> 1) * lda;
    } else {
      arow = A + (long)(row0 + r) * lda;
    }
    gA[j] = arow + gk;
    gB[j] = B + (long)(nt * 128 + r) * K + gk;
    lA[j] = ldsA + c * 8;
    lB[j] = ldsB + c * 8;
  }
  const int lane = tid & 63, wave = tid >> 6;
  const int wm = (wave & 1) * 64, wn = (wave >> 1) * 64;
  const int lrow = lane & 15;
  const int kchunk = lane >> 4;  // 0..3
  const int rsw = lrow & 7;

  f32x4 acc[4][4];
#pragma unroll
  for (int i = 0; i < 4; i++)
#pragma unroll
    for (int j = 0; j < 4; j++) acc[i][j] = f32x4{0.f, 0.f, 0.f, 0.f};

  const int nk = K >> 6;
  for (int kt = 0; kt < nk; ++kt) {
    const int kk = kt * 64;
#pragma unroll
    for (int j = 0; j < 4; j++) {
      GLL(gA[j] + kk, lA[j]);
      GLL(gB[j] + kk, lB[j]);
    }
    __syncthreads();
#pragma unroll
    for (int half = 0; half < 2; half++) {
      const int slot = (kchunk + half * 4) ^ rsw;
      bf16x8 af[4], bfv[4];
#pragma unroll
      for (int mi = 0; mi < 4; mi++)
        af[mi] = *(const bf16x8*)(ldsA + (wm + lrow + mi * 16) * 64 + slot * 8);
#pragma unroll
      for (int ni = 0; ni < 4; ni++)
        bfv[ni] = *(const bf16x8*)(ldsB + (wn + lrow + ni * 16) * 64 + slot * 8);
#pragma unroll
      for (int mi = 0; mi < 4; mi++)
#pragma unroll
        for (int ni = 0; ni < 4; ni++)
          acc[mi][ni] = __builtin_amdgcn_mfma_f32_16x16x32_bf16(af[mi], bfv[ni],
                                                                acc[mi][ni], 0, 0, 0);
    }
    __syncthreads();
  }

  // C/D layout: col = lane&15, row = (lane>>4)*4 + reg   [measured m89/m91]
  const int crow = row0 + wm + ((lane >> 4) << 2);
  const int ccol = nt * 128 + wn + (lane & 15);
#pragma unroll
  for (int mi = 0; mi < 4; mi++) {
#pragma unroll
    for (int ni = 0; ni < 4; ni++) {
#pragma unroll
      for (int r = 0; r < 4; r++) {
        int row = crow + mi * 16 + r;
        int col = ccol + ni * 16;
        float v = acc[mi][ni][r];
        if constexpr (CMODE == 0) {
          Cb[(long)row * ldc + col] = f2bf(v);
        } else if constexpr (CMODE == 1) {
          Cf[(long)row * ldc + col] = v;
        } else if constexpr (CMODE == 2) {
          int p = perm[row];
          if (p >= 0) atomicAdd(Cf + (long)(p >> 1) * ldc + col, topw[p] * v);
        } else {
          atomicAdd(Cf + (long)row * ldc + col, v);
        }
      }
    }
  }
}

// ---- fused [routed gu | shared gu]: 640 + 512 blocks ----
__global__ __launch_bounds__(256) void gemm_gu_fused(
    const u16* __restrict__ xb, const u16* __restrict__ wguT,
    const u16* __restrict__ sgsuT, u16* __restrict__ gur, u16* __restrict__ gus,
    const int* __restrict__ offp, const int* __restrict__ perm,
    const u16* __restrict__ zrow) {
  __shared__ __align__(16) u16 ldsA[8192], ldsB[8192];
  int bid = blockIdx.x;
  if (bid < 640) {
    gemm_body<0, true, true>(bid / 16, bid % 16, ldsA, ldsB, xb, HDIM, wguT,
                             (long)2 * IDIM * HDIM, HDIM, gur, nullptr, 2 * IDIM, offp,
                             perm, nullptr, zrow);
  } else {
    int b = bid - 640;
    gemm_body<0, false, false>(b / 32, b % 32, ldsA, ldsB, xb, HDIM, sgsuT, 0, HDIM, gus,
                               nullptr, 2 * ISDIM, nullptr, nullptr, nullptr, nullptr);
  }
}

// ---- fused [shared down fp32 store | routed down bf16 -> eo]: 256 + 640 blocks ----
__global__ __launch_bounds__(256) void gemm_down_plain(
    const u16* __restrict__ gus, const u16* __restrict__ sdT,
    const u16* __restrict__ gur, const u16* __restrict__ wdT, float* __restrict__ out,
    u16* __restrict__ eo, const int* __restrict__ offp) {
  __shared__ __align__(16) u16 ldsA[8192], ldsB[8192];
  int bid = blockIdx.x;
  if (bid < 256) {
    gemm_body<1, false, false>(bid / 16, bid % 16, ldsA, ldsB, gus, 2 * ISDIM, sdT, 0,
                               ISDIM, nullptr, out, HDIM, nullptr, nullptr, nullptr,
                               nullptr);
  } else {
    int b = bid - 256;
    gemm_body<0, false, true>(b / 16, b % 16, ldsA, ldsB, gur, 2 * IDIM, wdT,
                              (long)HDIM * IDIM, IDIM, eo, nullptr, HDIM, offp, nullptr,
                              nullptr, nullptr);
  }
}

// ---- combine: out[t] += w0*eo[r0] + w1*eo[r1] ----
__global__ __launch_bounds__(256) void combine_kernel(float* __restrict__ out,
                                                      const u16* __restrict__ eo,
                                                      const int* __restrict__ tokrow,
                                                      const float* __restrict__ topw) {
  const int t = blockIdx.x, tid = threadIdx.x;
  const long o = (long)t * HDIM + tid * 8;
  const int r0 = tokrow[t * 2], r1 = tokrow[t * 2 + 1];
  const float w0 = topw[t * 2], w1 = topw[t * 2 + 1];
  float4 a = *(const float4*)(out + o);
  float4 b = *(const float4*)(out + o + 4);
  uint4 e0 = *(const uint4*)(eo + (long)r0 * HDIM + tid * 8);
  uint4 e1 = *(const uint4*)(eo + (long)r1 * HDIM + tid * 8);
  const u32* p0 = &e0.x;
  const u32* p1 = &e1.x;
  float r[8] = {a.x, a.y, a.z, a.w, b.x, b.y, b.z, b.w};
#pragma unroll
  for (int j = 0; j < 4; j++) {
    r[j * 2 + 0] += w0 * bf2f((u16)(p0[j] & 0xFFFF)) + w1 * bf2f((u16)(p1[j] & 0xFFFF));
    r[j * 2 + 1] += w0 * bf2f((u16)(p0[j] >> 16)) + w1 * bf2f((u16)(p1[j] >> 16));
  }
  float4 oa = {r[0], r[1], r[2], r[3]};
  float4 ob = {r[4], r[5], r[6], r[7]};
  *(float4*)(out + o) = oa;
  *(float4*)(out + o + 4) = ob;
}

// ---- fallback kernels (small ws): atomic design ----
__global__ __launch_bounds__(256) void gemm_routed_gu(
    const u16* __restrict__ xb, const u16* __restrict__ wT, u16* __restrict__ Cb,
    const int* __restrict__ offp, const int* __restrict__ perm,
    const u16* __restrict__ zrow) {
  __shared__ __align__(16) u16 ldsA[8192], ldsB[8192];
  gemm_body<0, true, true>(blockIdx.y, blockIdx.x, ldsA, ldsB, xb, HDIM, wT,
                           (long)IDIM * HDIM, HDIM, Cb, nullptr, 2 * IDIM, offp, perm,
                           nullptr, zrow);
}
__global__ __launch_bounds__(256) void gemm_shared_gu(const u16* __restrict__ xb,
                                                      const u16* __restrict__ sgsuT,
                                                      u16* __restrict__ gus) {
  __shared__ __align__(16) u16 ldsA[8192], ldsB[8192];
  gemm_body<0, false, false>(blockIdx.y, blockIdx.x, ldsA, ldsB, xb, HDIM, sgsuT, 0, HDIM,
                             gus, nullptr, 2 * ISDIM, nullptr, nullptr, nullptr, nullptr);
}
__global__ __launch_bounds__(256) void gemm_down_atomic(
    const u16* __restrict__ gus, const u16* __restrict__ sdT,
    const u16* __restrict__ gur, const u16* __restrict__ wdT, float* __restrict__ out,
    const int* __restrict__ offp, const int* __restrict__ perm,
    const float* __restrict__ topw) {
  __shared__ __align__(16) u16 ldsA[8192], ldsB[8192];
  int bid = blockIdx.x;
  if (bid < 256) {
    gemm_body<3, false, false>(bid / 16, bid % 16, ldsA, ldsB, gus, 2 * ISDIM, sdT, 0,
                               ISDIM, nullptr, out, HDIM, nullptr, nullptr, nullptr,
                               nullptr);
  } else {
    int b = bid - 256;
    gemm_body<2, false, true>(b / 16, b % 16, ldsA, ldsB, gur, 2 * IDIM, wdT,
                              (long)HDIM * IDIM, IDIM, nullptr, out, HDIM, offp, perm,
                              topw, nullptr);
  }
}

extern "C" void kernel_launch(void* const* d_in, const int* in_sizes, int n_in,
                              void* d_out, int out_size, void* d_ws, size_t ws_size,
                              hipStream_t stream) {
  const float* x  = (const float*)d_in[0];
  const float* gw = (const float*)d_in[1];
  const float* wg = (const float*)d_in[2];
  const float* wu = (const float*)d_in[3];
  const float* wd = (const float*)d_in[4];
  const float* sg = (const float*)d_in[5];
  const float* su = (const float*)d_in[6];
  const float* sd = (const float*)d_in[7];
  float* out = (float*)d_out;

  char* ws = (char*)d_ws;
  size_t off = 0;
  auto alloc = [&](size_t b) {
    size_t o = off;
    off += (b + 255) & ~(size_t)255;
    return (void*)(ws + o);
  };
  u16*   xb     = (u16*)alloc((size_t)T_TOK * HDIM * 2);
  u16*   gur    = (u16*)alloc((size_t)MAXROWS * 2 * IDIM * 2);  // g|u, hr in cols 0..I
  u16*   gus    = (u16*)alloc((size_t)T_TOK * 2 * ISDIM * 2);   // gs|us, hs in cols 0..IS
  float* topw   = (float*)alloc((size_t)T_TOK * 2 * 4);
  int*   topi   = (int*)alloc((size_t)T_TOK * 2 * 4);
  int*   tokrow = (int*)alloc((size_t)T_TOK * 2 * 4);
  int*   perm   = (int*)alloc(8192 * 4);
  int*   meta   = (int*)alloc(64 * 4);
  u16*   zrow   = (u16*)alloc(4096);
  size_t base = off;

  const size_t SZ_WGUT  = (size_t)NEXP * 2 * IDIM * HDIM * 2;  // 64 MiB
  const size_t SZ_SGSUT = (size_t)2 * ISDIM * HDIM * 2;        // 16 MiB
  const size_t SZ_SDT   = (size_t)HDIM * ISDIM * 2;            // 8 MiB
  const size_t SZ_WDT   = (size_t)NEXP * HDIM * IDIM * 2;      // 32 MiB
  const bool fused = ws_size >= base + SZ_WGUT + SZ_SGSUT;

  init_kernel<<<32, 256, 0, stream>>>(perm, meta, (int*)zrow);
  gate_kernel<<<T_TOK, 256, 0, stream>>>(x, gw, xb, out, topw, topi, meta);
  scan_kernel<<<1, 64, 0, stream>>>(meta);
  assign_kernel<<<16, 256, 0, stream>>>(topi, meta, perm, tokrow);

  if (fused) {
    u16* wguT  = (u16*)(ws + base);
    u16* sgsuT = (u16*)(ws + base + SZ_WGUT);
    u16* sdT   = wguT;                              // reuse after gu gemm
    u16* wdT   = wguT + SZ_SDT / 2;                 // elements
    u16* eo    = wguT + (SZ_SDT + SZ_WDT) / 2;      // 20 MiB in free tail of region
    tcast_kernel<<<dim3(IDIM / 64, HDIM / 64, NEXP), 256, 0, stream>>>(
        wg, wguT, HDIM, IDIM, (long)HDIM * IDIM, (long)2 * IDIM * HDIM);
    tcast_kernel<<<dim3(IDIM / 64, HDIM / 64, NEXP), 256, 0, stream>>>(
        wu, wguT + (size_t)IDIM * HDIM, HDIM, IDIM, (long)HDIM * IDIM,
        (long)2 * IDIM * HDIM);
    tcast_kernel<<<dim3(ISDIM / 64, HDIM / 64, 1), 256, 0, stream>>>(sg, sgsuT, HDIM,
                                                                     ISDIM, 0, 0);
    tcast_kernel<<<dim3(ISDIM / 64, HDIM / 64, 1), 256, 0, stream>>>(
        su, sgsuT + (size_t)ISDIM * HDIM, HDIM, ISDIM, 0, 0);
    gemm_gu_fused<<<1152, 256, 0, stream>>>(xb, wguT, sgsuT, gur, gus, meta + 16, perm,
                                            zrow);
    silu_kernel<128><<<(MAXROWS * IDIM / 8) / 256, 256, 0, stream>>>(gur);
    silu_kernel<256><<<(T_TOK * ISDIM / 8) / 256, 256, 0, stream>>>(gus);
    tcast_kernel<<<dim3(HDIM / 64, ISDIM / 64, 1), 256, 0, stream>>>(sd, sdT, ISDIM,
                                                                     HDIM, 0, 0);
    tcast_kernel<<<dim3(HDIM / 64, IDIM / 64, NEXP), 256, 0, stream>>>(
        wd, wdT, IDIM, HDIM, (long)IDIM * HDIM, (long)HDIM * IDIM);
    gemm_down_plain<<<896, 256, 0, stream>>>(gus, sdT, gur, wdT, out, eo, meta + 16);
    combine_kernel<<<T_TOK, 256, 0, stream>>>(out, eo, tokrow, topw);
  } else {
    u16* wT    = (u16*)(ws + base);  // 40 MiB region, sequentially reused
    u16* sgsuT = wT;
    u16* sdT   = wT;
    u16* wdT   = wT + SZ_SDT / 2;
    tcast_kernel<<<dim3(IDIM / 64, HDIM / 64, NEXP), 256, 0, stream>>>(
        wg, wT, HDIM, IDIM, (long)HDIM * IDIM, (long)IDIM * HDIM);
    gemm_routed_gu<<<dim3(8, MAXROWS / 128), 256, 0, stream>>>(xb, wT, gur, meta + 16,
                                                               perm, zrow);
    tcast_kernel<<<dim3(IDIM / 64, HDIM / 64, NEXP), 256, 0, stream>>>(
        wu, wT, HDIM, IDIM, (long)HDIM * IDIM, (long)IDIM * HDIM);
    gemm_routed_gu<<<dim3(8, MAXROWS / 128), 256, 0, stream>>>(xb, wT, gur + IDIM,
                                                               meta + 16, perm, zrow);
    silu_kernel<128><<<(MAXROWS * IDIM / 8) / 256, 256, 0, stream>>>(gur);
    tcast_kernel<<<dim3(ISDIM / 64, HDIM / 64, 1), 256, 0, stream>>>(sg, sgsuT, HDIM,
                                                                     ISDIM, 0, 0);
    tcast_kernel<<<dim3(ISDIM / 64, HDIM / 64, 1), 256, 0, stream>>>(
        su, sgsuT + (size_t)ISDIM * HDIM, HDIM, ISDIM, 0, 0);
    gemm_shared_gu<<<dim3(32, 16), 256, 0, stream>>>(xb, sgsuT, gus);
    silu_kernel<256><<<(T_TOK * ISDIM / 8) / 256, 256, 0, stream>>>(gus);
    tcast_kernel<<<dim3(HDIM / 64, ISDIM / 64, 1), 256, 0, stream>>>(sd, sdT, ISDIM,
                                                                     HDIM, 0, 0);
    tcast_kernel<<<dim3(HDIM / 64, IDIM / 64, NEXP), 256, 0, stream>>>(
        wd, wdT, IDIM, HDIM, (long)IDIM * HDIM, (long)HDIM * IDIM);
    gemm_down_atomic<<<896, 256, 0, stream>>>(gus, sdT, gur, wdT, out, meta + 16, perm,
                                              topw);
  }
}